// Round 9
// baseline (445.452 us; speedup 1.0000x reference)
//
#include <hip/hip_runtime.h>
#include <hip/hip_bf16.h>

// LGCN2: N=10000 nodes, RP=16, E=LW=64, R=NT=8000 edges, C=16, NREL=50.
// Round 9: R8 + k_h2all edge loop restructured for ILP: each wave owns a
// CONTIGUOUS chunk of 32 edges (3750 waves x 32 = 120000 exactly) processed
// as 8 quads of 4 independent load->compute chains (latency-chain bound ->
// 4 chains in flight). r0 band likewise chunked (250 waves x 32 = 8000).

#define N_     10000
#define RP_    16
#define E_     64
#define R_     8000
#define NT_    8000
#define C_     16
#define BK_    32              // s-bucket capacity; max s-degree (Poisson 0.8) << 32

// ---- workspace layout (4-byte units) ----
// colsum  [0,       160000)  f  (zeroed)
// rowsum  [160000,  320000)  f  (zeroed)
// h2r0    [320000,  320064)  f  (zeroed)
// cnt     [320064,  330064)  i  (zeroed)
// done    [330064,  330065)  i  (zeroed)
// order2  [330080,  650080)  i  (t | o<<13; guarded by cnt)
// hbuf    [650080, 1290080)  f  (written, no zero needed)
// lat1t   [1290080,1418080)  f  [t*16+r] layout (gather broadcast reads)
// lat2    [1418080,1546080)  f  [r*8000+t] k-order (stage-2 coalescing)
#define WS_ZERO_UNITS 330080

__global__ void k_lat(const float* __restrict__ nhots,
                      const float* __restrict__ w1a, const float* __restrict__ b1a,
                      const float* __restrict__ w1b, const float* __restrict__ b1b,
                      const float* __restrict__ w2a, const float* __restrict__ b2a,
                      const float* __restrict__ w2b, const float* __restrict__ b2b,
                      const int* __restrict__ hind, const int* __restrict__ vind,
                      float* __restrict__ lat1t, float* __restrict__ lat2,
                      float* __restrict__ colsum, float* __restrict__ rowsum,
                      int* __restrict__ cnt, int* __restrict__ order2,
                      float* __restrict__ out, const float* __restrict__ bias2) {
    __shared__ float zb[4][128];
    __shared__ float r0[2];
    const int lane = threadIdx.x & 63;
    const int wv   = threadIdx.x >> 6;
    const int t    = blockIdx.x * 4 + wv;          // 2000*4 == 8000 exactly

    // fused out-init: 2000 blocks * 80 == 160000 exactly
    if (threadIdx.x < 80) {
        const int i = blockIdx.x * 80 + threadIdx.x;
        out[i] = bias2[i & 15];
    }

    // --- sparse gather: scan first 64 columns (hot col < NREL=50 < 64) ---
    const float v = nhots[(size_t)t * R_ + lane];
    float acc1 = 0.f, acc2 = 0.f;
    unsigned long long m = __ballot(v != 0.0f);
    while (m) {
        const int src = __ffsll(m) - 1;
        m &= m - 1;
        const float val = __shfl(v, src);
        acc1 += val * w1a[src * 64 + lane];
        acc2 += val * w2a[src * 64 + lane];
    }
    if (threadIdx.x == 0) { r0[0] = 0.f; r0[1] = 0.f; }
    zb[wv][lane]      = fmaxf(acc1 + b1a[lane], 0.f);
    zb[wv][64 + lane] = fmaxf(acc2 + b2a[lane], 0.f);
    __syncthreads();

    // --- 64->16 dense layer: lanes 0..15 do lat1, 16..31 do lat2 ---
    const int g = lane >> 4, r = lane & 15;
    float pre = 0.f;
    if (g < 2) {
        const float* wb = (g == 0) ? w1b : w2b;
        pre = ((g == 0) ? b1b : b2b)[r];
        const float* z = &zb[wv][g * 64];
        #pragma unroll
        for (int l = 0; l < 64; ++l) pre += z[l] * wb[l * 16 + r];
    }
    // --- softmax over the 16-lane group ---
    float mx = pre;
    #pragma unroll
    for (int mm = 8; mm >= 1; mm >>= 1) mx = fmaxf(mx, __shfl_xor(mx, mm, 16));
    const float e = expf(pre - mx);
    float s = e;
    #pragma unroll
    for (int mm = 8; mm >= 1; mm >>= 1) s += __shfl_xor(s, mm, 16);
    const float lt = e / s;

    const int s_t = hind[2 * t];                   // r=0 band: hrow == s[t]
    const int o_t = vind[2 * t + 1];               // r=0 band: vcol == o[t]
    if (g == 0) {
        lat1t[t * 16 + r] = lt;
        if (r) atomicAdd(colsum + o_t * r, lt);    // key hcol == o*r
        else   atomicAdd(&r0[0], lt);              // key-0 hotspot -> LDS pre-agg
    } else if (g == 1) {
        lat2[r * NT_ + t] = lt;
        if (r) atomicAdd(rowsum + s_t * r, lt);
        else   atomicAdd(&r0[1], lt);
    } else if (g == 2 && r == 0) {                 // idle lane: bucket insert
        const int pos = atomicAdd(cnt + s_t, 1);
        order2[s_t * BK_ + pos] = t | (o_t << 13); // t < 8192
    }
    __syncthreads();
    if (threadIdx.x == 0) atomicAdd(colsum, r0[0]);
    if (threadIdx.x == 1) atomicAdd(rowsum, r0[1]);
}

// gather: one wave per node n; h[n,l] = relu(bias1[l] + sum_{t in n} sum_r
//   (lat1[r,t]/colsum[o_t*r]) * weights1[o_t*r, l])
__global__ void k_hg(const float* __restrict__ lat1t, const float* __restrict__ colsum,
                     const int* __restrict__ cnt, const int* __restrict__ order2,
                     const float* __restrict__ w1,
                     const float* __restrict__ bias1, float* __restrict__ hbuf) {
    const int lane = threadIdx.x & 63;
    const int n = blockIdx.x * 4 + (threadIdx.x >> 6);  // 2500*4 == 10000 exactly
    const int m = cnt[n];
    float acc = 0.f;
    for (int j = 0; j < m; ++j) {
        const int e = order2[n * BK_ + j];
        const int t   = e & 8191;
        const int o_t = e >> 13;
        float ln = 0.f;
        if (lane < 16) ln = lat1t[t * 16 + lane] / colsum[o_t * lane];
        #pragma unroll
        for (int r = 0; r < 16; ++r) {
            const float a = __shfl(ln, r);
            acc += a * w1[(o_t * r) * 64 + lane];   // coalesced 256B row
        }
    }
    hbuf[n * 64 + lane] = fmaxf(acc + bias1[lane], 0.f);
}

// Stage 2, one dispatch, 1024-thread blocks, 256 blocks (1/CU):
//  blocks 0..239  : generic edges (k>=8000). Each wave owns 32 contiguous
//                   edges, processed as 8 quads of 4 independent chains.
//  blocks 240..255: r=0 band (chunked, 250 active waves of 32 t each) ->
//                   h2r0; LAST r0 block (ticket==15) applies w2[0]·h2r0.
__global__ void k_h2all(const float* __restrict__ lat2, const float* __restrict__ rowsum,
                        const int* __restrict__ vind, const float* __restrict__ hbuf,
                        const float* __restrict__ w2, float* __restrict__ out,
                        float* __restrict__ h2r0, int* __restrict__ done) {
    const int lane = threadIdx.x & 63;
    const int wv   = threadIdx.x >> 6;              // 0..15

    if (blockIdx.x >= 240) {                        // --- r0 reduction blocks ---
        __shared__ int is_last;
        const int wg = (blockIdx.x - 240) * 16 + wv; // 0..255
        float acc = 0.f;
        const int tb = wg * 32;                     // 250 waves cover 8000
        if (tb < NT_) {
            for (int t = tb; t < tb + 32; ++t) {
                const int vc = vind[2 * t + 1];
                acc += lat2[t] * hbuf[vc * 64 + lane];
            }
            acc /= rowsum[0];
            atomicAdd(&h2r0[lane], acc);
        }
        __threadfence();
        __syncthreads();                            // all waves' atomics done
        if (threadIdx.x == 0) is_last = (atomicAdd(done, 1) == 15);
        __syncthreads();
        if (is_last) {
            __threadfence();                        // acquire h2r0 writes
            if (threadIdx.x < 16) {
                const int c = threadIdx.x;
                float acc2 = 0.f;
                #pragma unroll
                for (int hh = 0; hh < 64; ++hh) acc2 += w2[hh * 16 + c] * h2r0[hh];
                atomicAdd(&out[c], acc2);
            }
        }
        return;
    }

    __shared__ float sw2[16384];                    // [rp][hh][c], 64KB
    for (int i = threadIdx.x; i < 16384; i += 1024) sw2[i] = w2[i];
    __syncthreads();

    const int c = lane & 15;
    const int quarter = lane >> 4;
    const int w = blockIdx.x * 16 + wv;             // 0..3839; 3750 active
    const int base = w * 32;
    if (base >= 120000) return;
    const int2* vp = reinterpret_cast<const int2*>(vind) + NT_ + base;
    const float* l2p = lat2 + NT_ + base;

    #pragma unroll 1
    for (int i = 0; i < 8; ++i) {
        int2 vv[4];
        float u[4], p[4];
        int rp[4], np[4];
        #pragma unroll
        for (int x = 0; x < 4; ++x) vv[x] = vp[i * 4 + x];
        #pragma unroll
        for (int x = 0; x < 4; ++x) {
            const float val = l2p[i * 4 + x] / rowsum[vv[x].x];
            u[x] = val * hbuf[vv[x].y * 64 + lane]; // coalesced 256B row
            rp[x] = vv[x].x / N_;
            np[x] = vv[x].x - rp[x] * N_;
            p[x] = 0.f;
        }
        #pragma unroll
        for (int j = 0; j < 16; ++j) {
            const int hh = quarter * 16 + ((j + quarter) & 15);
            #pragma unroll
            for (int x = 0; x < 4; ++x)
                p[x] += __shfl(u[x], hh) * sw2[rp[x] * 1024 + hh * 16 + c];
        }
        #pragma unroll
        for (int x = 0; x < 4; ++x) {
            p[x] += __shfl_xor(p[x], 16);
            p[x] += __shfl_xor(p[x], 32);
            if (quarter == 0) atomicAdd(&out[np[x] * 16 + c], p[x]);
        }
    }
}

extern "C" void kernel_launch(void* const* d_in, const int* in_sizes, int n_in,
                              void* d_out, int out_size, void* d_ws, size_t ws_size,
                              hipStream_t stream) {
    const float* nhots    = (const float*)d_in[0];
    const float* w1a      = (const float*)d_in[1];
    const float* b1a      = (const float*)d_in[2];
    const float* w1b      = (const float*)d_in[3];
    const float* b1b      = (const float*)d_in[4];
    const float* w2a      = (const float*)d_in[5];
    const float* b2a      = (const float*)d_in[6];
    const float* w2b      = (const float*)d_in[7];
    const float* b2b      = (const float*)d_in[8];
    const float* weights1 = (const float*)d_in[9];
    const float* bias1    = (const float*)d_in[10];
    const float* weights2 = (const float*)d_in[11];
    const float* bias2    = (const float*)d_in[12];
    const int*   hind     = (const int*)d_in[13];
    const int*   vind     = (const int*)d_in[14];
    float* out = (float*)d_out;

    float* ws     = (float*)d_ws;
    float* colsum = ws;
    float* rowsum = ws + 160000;
    float* h2r0   = ws + 320000;
    int*   cnt    = (int*)(ws + 320064);
    int*   done   = (int*)(ws + 330064);
    int*   order2 = (int*)(ws + 330080);
    float* hbuf   = ws + 650080;
    float* lat1t  = ws + 1290080;
    float* lat2   = ws + 1418080;

    hipMemsetAsync(d_ws, 0, WS_ZERO_UNITS * sizeof(float), stream);
    k_lat<<<2000, 256, 0, stream>>>(nhots, w1a, b1a, w1b, b1b, w2a, b2a, w2b, b2b,
                                    hind, vind, lat1t, lat2, colsum, rowsum, cnt,
                                    order2, out, bias2);
    k_hg<<<2500, 256, 0, stream>>>(lat1t, colsum, cnt, order2, weights1, bias1, hbuf);
    k_h2all<<<256, 1024, 0, stream>>>(lat2, rowsum, vind, hbuf, weights2, out, h2r0, done);
}

// Round 10
// 416.864 us; speedup vs baseline: 1.0686x; 1.0686x over previous
//
#include <hip/hip_runtime.h>
#include <hip/hip_bf16.h>

// LGCN2: N=10000 nodes, RP=16, E=LW=64, R=NT=8000 edges, C=16, NREL=50.
// Round 10: exact R8 structure (best: 415.8us); k_h2all grid 256 -> 512
// blocks (496 compute + 16 r0). 64KB LDS allows 2 blocks/CU -> 8 waves/SIMD,
// doubling TLP on the latency-chain-bound edge loop (the R7->R8 lever).
// R9's 4-way in-wave ILP regressed (register pressure/spills) - reverted.

#define N_     10000
#define RP_    16
#define E_     64
#define R_     8000
#define NT_    8000
#define C_     16
#define BK_    32              // s-bucket capacity; max s-degree (Poisson 0.8) << 32

// ---- workspace layout (4-byte units) ----
// colsum  [0,       160000)  f  (zeroed)
// rowsum  [160000,  320000)  f  (zeroed)
// h2r0    [320000,  320064)  f  (zeroed)
// cnt     [320064,  330064)  i  (zeroed)
// done    [330064,  330065)  i  (zeroed)
// order2  [330080,  650080)  i  (t | o<<13; guarded by cnt)
// hbuf    [650080, 1290080)  f  (written, no zero needed)
// lat1t   [1290080,1418080)  f  [t*16+r] layout (gather broadcast reads)
// lat2    [1418080,1546080)  f  [r*8000+t] k-order (stage-2 coalescing)
#define WS_ZERO_UNITS 330080

__global__ void k_lat(const float* __restrict__ nhots,
                      const float* __restrict__ w1a, const float* __restrict__ b1a,
                      const float* __restrict__ w1b, const float* __restrict__ b1b,
                      const float* __restrict__ w2a, const float* __restrict__ b2a,
                      const float* __restrict__ w2b, const float* __restrict__ b2b,
                      const int* __restrict__ hind, const int* __restrict__ vind,
                      float* __restrict__ lat1t, float* __restrict__ lat2,
                      float* __restrict__ colsum, float* __restrict__ rowsum,
                      int* __restrict__ cnt, int* __restrict__ order2,
                      float* __restrict__ out, const float* __restrict__ bias2) {
    __shared__ float zb[4][128];
    __shared__ float r0[2];
    const int lane = threadIdx.x & 63;
    const int wv   = threadIdx.x >> 6;
    const int t    = blockIdx.x * 4 + wv;          // 2000*4 == 8000 exactly

    // fused out-init: 2000 blocks * 80 == 160000 exactly
    if (threadIdx.x < 80) {
        const int i = blockIdx.x * 80 + threadIdx.x;
        out[i] = bias2[i & 15];
    }

    // --- sparse gather: scan first 64 columns (hot col < NREL=50 < 64) ---
    const float v = nhots[(size_t)t * R_ + lane];
    float acc1 = 0.f, acc2 = 0.f;
    unsigned long long m = __ballot(v != 0.0f);
    while (m) {
        const int src = __ffsll(m) - 1;
        m &= m - 1;
        const float val = __shfl(v, src);
        acc1 += val * w1a[src * 64 + lane];
        acc2 += val * w2a[src * 64 + lane];
    }
    if (threadIdx.x == 0) { r0[0] = 0.f; r0[1] = 0.f; }
    zb[wv][lane]      = fmaxf(acc1 + b1a[lane], 0.f);
    zb[wv][64 + lane] = fmaxf(acc2 + b2a[lane], 0.f);
    __syncthreads();

    // --- 64->16 dense layer: lanes 0..15 do lat1, 16..31 do lat2 ---
    const int g = lane >> 4, r = lane & 15;
    float pre = 0.f;
    if (g < 2) {
        const float* wb = (g == 0) ? w1b : w2b;
        pre = ((g == 0) ? b1b : b2b)[r];
        const float* z = &zb[wv][g * 64];
        #pragma unroll
        for (int l = 0; l < 64; ++l) pre += z[l] * wb[l * 16 + r];
    }
    // --- softmax over the 16-lane group ---
    float mx = pre;
    #pragma unroll
    for (int mm = 8; mm >= 1; mm >>= 1) mx = fmaxf(mx, __shfl_xor(mx, mm, 16));
    const float e = expf(pre - mx);
    float s = e;
    #pragma unroll
    for (int mm = 8; mm >= 1; mm >>= 1) s += __shfl_xor(s, mm, 16);
    const float lt = e / s;

    const int s_t = hind[2 * t];                   // r=0 band: hrow == s[t]
    const int o_t = vind[2 * t + 1];               // r=0 band: vcol == o[t]
    if (g == 0) {
        lat1t[t * 16 + r] = lt;
        if (r) atomicAdd(colsum + o_t * r, lt);    // key hcol == o*r
        else   atomicAdd(&r0[0], lt);              // key-0 hotspot -> LDS pre-agg
    } else if (g == 1) {
        lat2[r * NT_ + t] = lt;
        if (r) atomicAdd(rowsum + s_t * r, lt);
        else   atomicAdd(&r0[1], lt);
    } else if (g == 2 && r == 0) {                 // idle lane: bucket insert
        const int pos = atomicAdd(cnt + s_t, 1);
        order2[s_t * BK_ + pos] = t | (o_t << 13); // t < 8192
    }
    __syncthreads();
    if (threadIdx.x == 0) atomicAdd(colsum, r0[0]);
    if (threadIdx.x == 1) atomicAdd(rowsum, r0[1]);
}

// gather: one wave per node n; h[n,l] = relu(bias1[l] + sum_{t in n} sum_r
//   (lat1[r,t]/colsum[o_t*r]) * weights1[o_t*r, l])
__global__ void k_hg(const float* __restrict__ lat1t, const float* __restrict__ colsum,
                     const int* __restrict__ cnt, const int* __restrict__ order2,
                     const float* __restrict__ w1,
                     const float* __restrict__ bias1, float* __restrict__ hbuf) {
    const int lane = threadIdx.x & 63;
    const int n = blockIdx.x * 4 + (threadIdx.x >> 6);  // 2500*4 == 10000 exactly
    const int m = cnt[n];
    float acc = 0.f;
    for (int j = 0; j < m; ++j) {
        const int e = order2[n * BK_ + j];
        const int t   = e & 8191;
        const int o_t = e >> 13;
        float ln = 0.f;
        if (lane < 16) ln = lat1t[t * 16 + lane] / colsum[o_t * lane];
        #pragma unroll
        for (int r = 0; r < 16; ++r) {
            const float a = __shfl(ln, r);
            acc += a * w1[(o_t * r) * 64 + lane];   // coalesced 256B row
        }
    }
    hbuf[n * 64 + lane] = fmaxf(acc + bias1[lane], 0.f);
}

// Stage 2, one dispatch, 1024-thread blocks, 512 blocks (2/CU):
//  blocks 0..495  : generic edges (k>=8000), wave-per-edge, strided.
//  blocks 496..511: r=0 band (16 waves each; 256 partials) block reduction
//                   into h2r0; LAST r0 block (ticket==15) applies w2[0]·h2r0.
__global__ void k_h2all(const float* __restrict__ lat2, const float* __restrict__ rowsum,
                        const int* __restrict__ vind, const float* __restrict__ hbuf,
                        const float* __restrict__ w2, float* __restrict__ out,
                        float* __restrict__ h2r0, int* __restrict__ done) {
    const int lane = threadIdx.x & 63;
    const int wv   = threadIdx.x >> 6;              // 0..15

    if (blockIdx.x >= 496) {                        // --- r0 reduction blocks ---
        __shared__ int is_last;
        const int wg = (blockIdx.x - 496) * 16 + wv; // 0..255
        float acc = 0.f;
        for (int t = wg; t < NT_; t += 256) {
            const int vc = vind[2 * t + 1];
            acc += lat2[t] * hbuf[vc * 64 + lane];
        }
        acc /= rowsum[0];
        atomicAdd(&h2r0[lane], acc);
        __threadfence();
        __syncthreads();                            // all waves' atomics done
        if (threadIdx.x == 0) is_last = (atomicAdd(done, 1) == 15);
        __syncthreads();
        if (is_last) {
            __threadfence();                        // acquire h2r0 writes
            if (threadIdx.x < 16) {
                const int c = threadIdx.x;
                float acc2 = 0.f;
                #pragma unroll
                for (int hh = 0; hh < 64; ++hh) acc2 += w2[hh * 16 + c] * h2r0[hh];
                atomicAdd(&out[c], acc2);
            }
        }
        return;
    }

    __shared__ float sw2[16384];                    // [rp][hh][c], 64KB
    for (int i = threadIdx.x; i < 16384; i += 1024) sw2[i] = w2[i];
    __syncthreads();

    const int c = lane & 15;
    const int quarter = lane >> 4;
    for (int e = blockIdx.x * 16 + wv; e < 120000; e += 496 * 16) {
        const int k  = NT_ + e;
        const int2 vv = reinterpret_cast<const int2*>(vind)[k];
        const int q  = vv.x;
        const int vc = vv.y;
        const float val = lat2[k] / rowsum[q];
        const int rp = q / N_;
        const int np = q - rp * N_;
        const float u = val * hbuf[vc * 64 + lane]; // coalesced 256B row
        float partial = 0.f;
        #pragma unroll
        for (int j = 0; j < 16; ++j) {
            const int hh = quarter * 16 + ((j + quarter) & 15);
            const float hv = __shfl(u, hh);
            partial += hv * sw2[rp * 1024 + hh * 16 + c];
        }
        partial += __shfl_xor(partial, 16);
        partial += __shfl_xor(partial, 32);
        if (quarter == 0) atomicAdd(&out[np * 16 + c], partial);
    }
}

extern "C" void kernel_launch(void* const* d_in, const int* in_sizes, int n_in,
                              void* d_out, int out_size, void* d_ws, size_t ws_size,
                              hipStream_t stream) {
    const float* nhots    = (const float*)d_in[0];
    const float* w1a      = (const float*)d_in[1];
    const float* b1a      = (const float*)d_in[2];
    const float* w1b      = (const float*)d_in[3];
    const float* b1b      = (const float*)d_in[4];
    const float* w2a      = (const float*)d_in[5];
    const float* b2a      = (const float*)d_in[6];
    const float* w2b      = (const float*)d_in[7];
    const float* b2b      = (const float*)d_in[8];
    const float* weights1 = (const float*)d_in[9];
    const float* bias1    = (const float*)d_in[10];
    const float* weights2 = (const float*)d_in[11];
    const float* bias2    = (const float*)d_in[12];
    const int*   hind     = (const int*)d_in[13];
    const int*   vind     = (const int*)d_in[14];
    float* out = (float*)d_out;

    float* ws     = (float*)d_ws;
    float* colsum = ws;
    float* rowsum = ws + 160000;
    float* h2r0   = ws + 320000;
    int*   cnt    = (int*)(ws + 320064);
    int*   done   = (int*)(ws + 330064);
    int*   order2 = (int*)(ws + 330080);
    float* hbuf   = ws + 650080;
    float* lat1t  = ws + 1290080;
    float* lat2   = ws + 1418080;

    hipMemsetAsync(d_ws, 0, WS_ZERO_UNITS * sizeof(float), stream);
    k_lat<<<2000, 256, 0, stream>>>(nhots, w1a, b1a, w1b, b1b, w2a, b2a, w2b, b2b,
                                    hind, vind, lat1t, lat2, colsum, rowsum, cnt,
                                    order2, out, bias2);
    k_hg<<<2500, 256, 0, stream>>>(lat1t, colsum, cnt, order2, weights1, bias1, hbuf);
    k_h2all<<<512, 1024, 0, stream>>>(lat2, rowsum, vind, hbuf, weights2, out, h2r0, done);
}